// Round 1
// baseline (34135.205 us; speedup 1.0000x reference)
//
#include <hip/hip_runtime.h>
#include <stdint.h>
#include <stddef.h>

// MambaBlock on MI355X (gfx950).
// out = OutProj( scan_t( s_t = tanh(A(g_t*s_{t-1}) + v_t) ) )
// with v = ((1-g)*inp)@A^T + inp@B^T hoisted into one K=2048 GEMM (gate depends
// only on inp, not on state). All GEMMs bf16 MFMA 16x16x32, fp32 accumulate.
// Scan: 64 waves, A-rows resident in VGPR MFMA fragments, one device-scope
// barrier per step (parallel arrival slots + 16-lane poll + acquire fence).

#define DIM   1024
#define SEQ   4096
#define NB    8
#define NTOK  (NB*SEQ)   // 32768

typedef __attribute__((ext_vector_type(8))) short          short8;
typedef __attribute__((ext_vector_type(4))) float          float4v;
typedef __attribute__((ext_vector_type(4))) int            int4v;
typedef __attribute__((ext_vector_type(4))) unsigned short ushort4v;

__device__ __forceinline__ unsigned short f2b(float f) {
  union { float f; unsigned int u; } v; v.f = f;
  return (unsigned short)((v.u + 0x7FFFu + ((v.u >> 16) & 1u)) >> 16);   // RNE
}
__device__ __forceinline__ float b2f(unsigned short h) {
  union { unsigned int u; float f; } v; v.u = ((unsigned int)h) << 16;
  return v.f;
}

// ---------------------------------------------------------------- small prep
__global__ void cast_bf16(const float* __restrict__ src,
                          unsigned short* __restrict__ dst, int n) {
  int i4 = (blockIdx.x * blockDim.x + threadIdx.x) * 4;
  if (i4 >= n) return;
  float4v v = *(const float4v*)(src + i4);
  ushort4v o;
  o[0] = f2b(v[0]); o[1] = f2b(v[1]); o[2] = f2b(v[2]); o[3] = f2b(v[3]);
  *(ushort4v*)(dst + i4) = o;
}

// Wcat[e][0:1024] = B[e][:], Wcat[e][1024:2048] = A[e][:]; Ab = bf16(A)
__global__ void build_wcat(const float* __restrict__ Bm, const float* __restrict__ A,
                           unsigned short* __restrict__ Wcat,
                           unsigned short* __restrict__ Ab) {
  int i4 = (blockIdx.x * 256 + threadIdx.x) * 4;       // 0..1048572
  int e = i4 >> 10, d = i4 & 1023;
  float4v bv = *(const float4v*)(Bm + i4);
  float4v av = *(const float4v*)(A + i4);
  ushort4v bb, ab;
  #pragma unroll
  for (int r = 0; r < 4; r++) { bb[r] = f2b(bv[r]); ab[r] = f2b(av[r]); }
  *(ushort4v*)(Wcat + (size_t)e * 2048 + d) = bb;
  *(ushort4v*)(Wcat + (size_t)e * 2048 + 1024 + d) = ab;
  *(ushort4v*)(Ab + i4) = ab;
}

__global__ void zero_u32(unsigned int* __restrict__ p, int n) {
  int i = blockIdx.x * 256 + threadIdx.x;
  if (i < n) p[i] = 0u;
}

// ---------------------------------------------------------------- GEMM (NT)
// C[m,n] = sum_k Ag[m,k]*Bg[n,k]  (both K-contiguous), 128x128 tile, BK=64.
// LDS rows padded to 72 elems (144B = +4 banks/row) -> conflict-free b128.
// EPI: 0 inp->inpq[:, :1024] bf16 | 1 gate->gscan bf16 + q->inpq[:,1024:]
//      2 v->fp32 [t*8+b][e]       | 3 out->fp32 [b*4096+t][e]
template<int EPI>
__global__ __launch_bounds__(256, 2)
void gemm_nt(const unsigned short* __restrict__ Ag, int lda,
             const unsigned short* __restrict__ Bg, int ldb,
             int K,
             const float* __restrict__ bias,
             void* __restrict__ out0,
             unsigned short* __restrict__ out1,
             const unsigned short* __restrict__ aux) {
  __shared__ unsigned short sA[128 * 72];
  __shared__ unsigned short sB[128 * 72];
  const int tid  = threadIdx.x;
  const int lane = tid & 63;
  const int wave = tid >> 6;
  const int wm = wave & 1, wn = wave >> 1;
  const int m0 = blockIdx.x * 128;
  const int n0 = blockIdx.y * 128;
  const int q  = lane >> 4;
  const int ln = lane & 15;

  float4v acc[4][4];
  const float4v fz = {0.f, 0.f, 0.f, 0.f};
  #pragma unroll
  for (int i = 0; i < 4; i++)
    #pragma unroll
    for (int j = 0; j < 4; j++) acc[i][j] = fz;

  for (int kk = 0; kk < K; kk += 64) {
    __syncthreads();                       // protect LDS reuse
    #pragma unroll
    for (int s = 0; s < 4; s++) {          // stage 128x64 of A and B
      int chunk = tid + s * 256;           // 0..1023 : row*8 + c
      int row = chunk >> 3, c = chunk & 7;
      int4v va = *(const int4v*)(Ag + (size_t)(m0 + row) * lda + kk + c * 8);
      int4v vb = *(const int4v*)(Bg + (size_t)(n0 + row) * ldb + kk + c * 8);
      *(int4v*)(sA + row * 72 + c * 8) = va;
      *(int4v*)(sB + row * 72 + c * 8) = vb;
    }
    __syncthreads();
    #pragma unroll
    for (int ks = 0; ks < 64; ks += 32) {
      short8 af[4], bf[4];
      #pragma unroll
      for (int i = 0; i < 4; i++)
        af[i] = *(const short8*)(sA + (wm * 64 + i * 16 + ln) * 72 + ks + q * 8);
      #pragma unroll
      for (int j = 0; j < 4; j++)
        bf[j] = *(const short8*)(sB + (wn * 64 + j * 16 + ln) * 72 + ks + q * 8);
      #pragma unroll
      for (int i = 0; i < 4; i++)
        #pragma unroll
        for (int j = 0; j < 4; j++)
          acc[i][j] = __builtin_amdgcn_mfma_f32_16x16x32_bf16(af[i], bf[j], acc[i][j], 0, 0, 0);
    }
  }

  #pragma unroll
  for (int j = 0; j < 4; j++) {
    const int gn = n0 + wn * 64 + j * 16 + ln;      // N index (feature e)
    const float bval = (EPI == 2) ? 0.f : bias[gn];
    #pragma unroll
    for (int i = 0; i < 4; i++) {
      const int gm = m0 + wm * 64 + i * 16 + q * 4; // M index (token row)
      #pragma unroll
      for (int r = 0; r < 4; r++) {
        const int row = gm + r;
        float vv = acc[i][j][r] + bval;
        if constexpr (EPI == 0) {
          ((unsigned short*)out0)[(size_t)row * 2048 + gn] = f2b(vv);
        } else if constexpr (EPI == 1) {
          float g = 1.f / (1.f + __expf(-vv));
          int t = row & (SEQ - 1), b = row >> 12;   // token row = b*SEQ + t
          ((unsigned short*)out0)[(size_t)(t * NB + b) * DIM + gn] = f2b(g);
          float iv = b2f(aux[(size_t)row * 2048 + gn]);
          out1[(size_t)row * 2048 + 1024 + gn] = f2b((1.f - g) * iv);
        } else if constexpr (EPI == 2) {
          int t = row & (SEQ - 1), b = row >> 12;
          ((float*)out0)[(size_t)(t * NB + b) * DIM + gn] = vv;
        } else {                                    // row = t*8 + b
          int b = row & 7, t = row >> 3;
          ((float*)out0)[(size_t)(b * SEQ + t) * DIM + gn] = vv;
        }
      }
    }
  }
}

// ---------------------------------------------------------------- scan
// 16 WGs x 256 thr = 64 waves; wave gw owns e-rows [16*gw, 16*gw+16).
// A fragments resident in VGPRs; per step: load m (bf16 [8][1024]) -> 32 MFMAs
// -> s = tanh(acc + v) -> write sb, m_next = g_{t+1}*s (sc1 atomic stores)
// -> parallel-slot device barrier.
__global__ __launch_bounds__(256, 1)
void scan_kernel(const unsigned short* __restrict__ Ab,     // [1024][1024] bf16
                 const unsigned short* __restrict__ gscan,  // [t*8+b][1024] bf16
                 const float* __restrict__ vflat,           // [t*8+b][1024] f32
                 unsigned short* __restrict__ sb,           // [t*8+b][1024] bf16
                 unsigned short* __restrict__ mbuf,         // [2][8][1024] bf16
                 unsigned int* __restrict__ slots) {        // [16]
  const int tid  = threadIdx.x;
  const int lane = tid & 63;
  const int wave = tid >> 6;
  const int gw   = blockIdx.x * 4 + wave;    // 0..63
  const int e0   = gw * 16;
  const int q    = lane >> 4;
  const int ln   = lane & 15;
  const int bcl  = ln & 7;                   // clamped batch (n>=8 unused cols)
  const bool active = (ln < 8);
  const int eb = e0 + q * 4;

  short8 af[32];                             // A rows in registers (128 VGPRs)
  #pragma unroll
  for (int ks = 0; ks < 32; ks++)
    af[ks] = *(const short8*)(Ab + (size_t)(e0 + ln) * 1024 + ks * 32 + q * 8);

  const float4v fz = {0.f, 0.f, 0.f, 0.f};

  for (int t = 0; t < SEQ; t++) {
    // prefetch v_t and g_{t+1} (barrier-independent, read-only)
    float4v vv = fz;
    ushort4v g4 = {0, 0, 0, 0};
    size_t rowoff = (size_t)(t * NB + bcl) * DIM + eb;
    if (active) {
      vv = *(const float4v*)(vflat + rowoff);
      if (t < SEQ - 1)
        g4 = *(const ushort4v*)(gscan + (size_t)((t + 1) * NB + bcl) * DIM + eb);
    }

    const unsigned short* mb = mbuf + (size_t)(t & 1) * (NB * DIM);
    float4v a0 = fz, a1 = fz, a2 = fz, a3 = fz;
    #pragma unroll
    for (int ks = 0; ks < 32; ks += 4) {
      short8 f0 = *(const short8*)(mb + bcl * DIM + (ks + 0) * 32 + q * 8);
      short8 f1 = *(const short8*)(mb + bcl * DIM + (ks + 1) * 32 + q * 8);
      short8 f2 = *(const short8*)(mb + bcl * DIM + (ks + 2) * 32 + q * 8);
      short8 f3 = *(const short8*)(mb + bcl * DIM + (ks + 3) * 32 + q * 8);
      a0 = __builtin_amdgcn_mfma_f32_16x16x32_bf16(af[ks + 0], f0, a0, 0, 0, 0);
      a1 = __builtin_amdgcn_mfma_f32_16x16x32_bf16(af[ks + 1], f1, a1, 0, 0, 0);
      a2 = __builtin_amdgcn_mfma_f32_16x16x32_bf16(af[ks + 2], f2, a2, 0, 0, 0);
      a3 = __builtin_amdgcn_mfma_f32_16x16x32_bf16(af[ks + 3], f3, a3, 0, 0, 0);
    }

    if (active) {
      float sv[4];
      #pragma unroll
      for (int r = 0; r < 4; r++) {
        float xx = a0[r] + a1[r] + a2[r] + a3[r] + vv[r];
        float ex = __expf(-2.f * fabsf(xx));
        float th = (1.f - ex) / (1.f + ex);
        sv[r] = copysignf(th, xx);
      }
      ushort4v sp;
      #pragma unroll
      for (int r = 0; r < 4; r++) sp[r] = f2b(sv[r]);
      *(ushort4v*)(sb + rowoff) = sp;                       // state for out-proj
      if (t < SEQ - 1) {                                    // m_{t+1} = g*s
        unsigned int w0 = (unsigned int)f2b(b2f(g4[0]) * sv[0]) |
                          ((unsigned int)f2b(b2f(g4[1]) * sv[1]) << 16);
        unsigned int w1 = (unsigned int)f2b(b2f(g4[2]) * sv[2]) |
                          ((unsigned int)f2b(b2f(g4[3]) * sv[3]) << 16);
        unsigned int* mn = (unsigned int*)(mbuf + (size_t)((t + 1) & 1) * (NB * DIM)
                                           + bcl * DIM + eb);
        // device-scope (sc1) stores: visible at L3 once vmcnt retires, no wbl2
        __hip_atomic_store(mn,     w0, __ATOMIC_RELAXED, __HIP_MEMORY_SCOPE_AGENT);
        __hip_atomic_store(mn + 1, w1, __ATOMIC_RELAXED, __HIP_MEMORY_SCOPE_AGENT);
      }
    }

    if (t == SEQ - 1) break;                 // no barrier after last step

    __syncthreads();                         // drains each wave's vmcnt
    if (wave == 0) {
      if (lane == 0)
        __hip_atomic_store(slots + blockIdx.x, (unsigned int)(t + 1),
                           __ATOMIC_RELAXED, __HIP_MEMORY_SCOPE_AGENT);
      const unsigned int target = (unsigned int)(t + 1);
      for (;;) {
        unsigned int s16 = __hip_atomic_load(slots + (lane & 15),
                                             __ATOMIC_RELAXED, __HIP_MEMORY_SCOPE_AGENT);
        if (__all(s16 >= target)) break;
        __builtin_amdgcn_s_sleep(1);
      }
      __builtin_amdgcn_fence(__ATOMIC_ACQUIRE, "agent");    // inval L1/L2
    }
    __syncthreads();
  }
}

// ---------------------------------------------------------------- launch
extern "C" void kernel_launch(void* const* d_in, const int* in_sizes, int n_in,
                              void* d_out, int out_size, void* d_ws, size_t ws_size,
                              hipStream_t stream) {
  const float* x      = (const float*)d_in[0];
  const float* A      = (const float*)d_in[1];
  const float* Bm     = (const float*)d_in[2];
  const float* W_in   = (const float*)d_in[3];
  const float* b_in   = (const float*)d_in[4];
  const float* W_gate = (const float*)d_in[5];
  const float* b_gate = (const float*)d_in[6];
  const float* W_out  = (const float*)d_in[7];
  const float* b_out  = (const float*)d_in[8];

  char* ws = (char*)d_ws;
  // workspace layout (~268 MB total)
  unsigned short* xb      = (unsigned short*)(ws);                 // 64 MB (reused as sb)
  unsigned short* inpq    = (unsigned short*)(ws + 67108864);      // 128 MB [n][2048]
  unsigned short* gscan   = (unsigned short*)(ws + 201326592);     // 64 MB
  unsigned short* Wb_in   = (unsigned short*)(ws + 268435456);     // 2 MB
  unsigned short* Wb_gate = (unsigned short*)(ws + 270532608);     // 2 MB
  unsigned short* Wb_out  = (unsigned short*)(ws + 272629760);     // 2 MB
  unsigned short* Wcat    = (unsigned short*)(ws + 274726912);     // 4 MB [e][2048]
  unsigned short* Ab      = (unsigned short*)(ws + 278921216);     // 2 MB
  unsigned short* mbuf    = (unsigned short*)(ws + 281018368);     // 32 KB (2x8x1024)
  unsigned int*   slots   = (unsigned int*)(ws + 281051136);       // 64 B
  float*          vflat   = (float*)d_out;          // v lives in d_out pre-scan
  unsigned short* sbuf    = xb;                     // states overwrite xb

  // prep
  cast_bf16<<<(33554432 / 4 + 255) / 256, 256, 0, stream>>>(x, xb, 33554432);
  cast_bf16<<<1024, 256, 0, stream>>>(W_in,   Wb_in,   1048576);
  cast_bf16<<<1024, 256, 0, stream>>>(W_gate, Wb_gate, 1048576);
  cast_bf16<<<1024, 256, 0, stream>>>(W_out,  Wb_out,  1048576);
  build_wcat<<<1024, 256, 0, stream>>>(Bm, A, Wcat, Ab);
  zero_u32<<<(8192 + 16 + 255) / 256, 256, 0, stream>>>((unsigned int*)mbuf, 8192 + 16);

  dim3 grid(NTOK / 128, DIM / 128);
  // inp = x @ W_in^T + b_in
  gemm_nt<0><<<grid, 256, 0, stream>>>(xb, DIM, Wb_in, DIM, DIM, b_in,
                                       (void*)inpq, nullptr, nullptr);
  // g = sigmoid(inp @ W_gate^T + b_gate); q = (1-g)*inp
  gemm_nt<1><<<grid, 256, 0, stream>>>(inpq, 2048, Wb_gate, DIM, DIM, b_gate,
                                       (void*)gscan, inpq, inpq);
  // v = [inp, q] @ [B; A]^T   (K = 2048)
  gemm_nt<2><<<grid, 256, 0, stream>>>(inpq, 2048, Wcat, 2048, 2048, b_in,
                                       (void*)vflat, nullptr, nullptr);
  // sequential scan
  scan_kernel<<<16, 256, 0, stream>>>(Ab, gscan, vflat, sbuf, mbuf, slots);
  // out = states @ W_out^T + b_out  (with [t*8+b] -> [b*4096+t] permute)
  gemm_nt<3><<<grid, 256, 0, stream>>>(sbuf, DIM, Wb_out, DIM, DIM, b_out,
                                       (void*)d_out, nullptr, nullptr);
}

// Round 2
// 30468.637 us; speedup vs baseline: 1.1203x; 1.1203x over previous
//
#include <hip/hip_runtime.h>
#include <stdint.h>
#include <stddef.h>

// MambaBlock on MI355X (gfx950).
// out = OutProj( scan_t( s_t = tanh(A(g_t*s_{t-1}) + v_t) ) )
// with v = ((1-g)*inp)@A^T + inp@B^T hoisted into one K=2048 GEMM.
// Scan: 64 waves, A-rows resident in VGPR MFMA fragments.
// Sync (round 2): fence-free device protocol — m-vector moves via explicit
// sc0 sc1 (LLC-direct) asm loads/stores; per-wave flags; every wave polls all
// 64 flags itself. No __syncthreads, no acquire fence -> L1/L2 stay warm for
// vflat/gscan/sb streams.

#define DIM   1024
#define SEQ   4096
#define NB    8
#define NTOK  (NB*SEQ)   // 32768

typedef __attribute__((ext_vector_type(8))) short          short8;
typedef __attribute__((ext_vector_type(4))) float          float4v;
typedef __attribute__((ext_vector_type(4))) int            int4v;
typedef __attribute__((ext_vector_type(4))) unsigned short ushort4v;

__device__ __forceinline__ unsigned short f2b(float f) {
  union { float f; unsigned int u; } v; v.f = f;
  return (unsigned short)((v.u + 0x7FFFu + ((v.u >> 16) & 1u)) >> 16);   // RNE
}
__device__ __forceinline__ float b2f(unsigned short h) {
  union { unsigned int u; float f; } v; v.u = ((unsigned int)h) << 16;
  return v.f;
}

// ---------------------------------------------------------------- small prep
__global__ void cast_bf16(const float* __restrict__ src,
                          unsigned short* __restrict__ dst, int n) {
  int i4 = (blockIdx.x * blockDim.x + threadIdx.x) * 4;
  if (i4 >= n) return;
  float4v v = *(const float4v*)(src + i4);
  ushort4v o;
  o[0] = f2b(v[0]); o[1] = f2b(v[1]); o[2] = f2b(v[2]); o[3] = f2b(v[3]);
  *(ushort4v*)(dst + i4) = o;
}

// Wcat[e][0:1024] = B[e][:], Wcat[e][1024:2048] = A[e][:]; Ab = bf16(A)
__global__ void build_wcat(const float* __restrict__ Bm, const float* __restrict__ A,
                           unsigned short* __restrict__ Wcat,
                           unsigned short* __restrict__ Ab) {
  int i4 = (blockIdx.x * 256 + threadIdx.x) * 4;       // 0..1048572
  int e = i4 >> 10, d = i4 & 1023;
  float4v bv = *(const float4v*)(Bm + i4);
  float4v av = *(const float4v*)(A + i4);
  ushort4v bb, ab;
  #pragma unroll
  for (int r = 0; r < 4; r++) { bb[r] = f2b(bv[r]); ab[r] = f2b(av[r]); }
  *(ushort4v*)(Wcat + (size_t)e * 2048 + d) = bb;
  *(ushort4v*)(Wcat + (size_t)e * 2048 + 1024 + d) = ab;
  *(ushort4v*)(Ab + i4) = ab;
}

__global__ void zero_u32(unsigned int* __restrict__ p, int n) {
  int i = blockIdx.x * 256 + threadIdx.x;
  if (i < n) p[i] = 0u;
}

// ---------------------------------------------------------------- GEMM (NT)
// C[m,n] = sum_k Ag[m,k]*Bg[n,k]  (both K-contiguous), 128x128 tile, BK=64.
// LDS rows padded to 72 elems -> conflict-free b128.
// EPI: 0 inp->inpq[:, :1024] bf16 | 1 gate->gscan bf16 + q->inpq[:,1024:]
//      2 v->fp32 [t*8+b][e]       | 3 out->fp32 [b*4096+t][e]
template<int EPI>
__global__ __launch_bounds__(256, 2)
void gemm_nt(const unsigned short* __restrict__ Ag, int lda,
             const unsigned short* __restrict__ Bg, int ldb,
             int K,
             const float* __restrict__ bias,
             void* __restrict__ out0,
             unsigned short* __restrict__ out1,
             const unsigned short* __restrict__ aux) {
  __shared__ unsigned short sA[128 * 72];
  __shared__ unsigned short sB[128 * 72];
  const int tid  = threadIdx.x;
  const int lane = tid & 63;
  const int wave = tid >> 6;
  const int wm = wave & 1, wn = wave >> 1;
  const int m0 = blockIdx.x * 128;
  const int n0 = blockIdx.y * 128;
  const int q  = lane >> 4;
  const int ln = lane & 15;

  float4v acc[4][4];
  const float4v fz = {0.f, 0.f, 0.f, 0.f};
  #pragma unroll
  for (int i = 0; i < 4; i++)
    #pragma unroll
    for (int j = 0; j < 4; j++) acc[i][j] = fz;

  for (int kk = 0; kk < K; kk += 64) {
    __syncthreads();                       // protect LDS reuse
    #pragma unroll
    for (int s = 0; s < 4; s++) {          // stage 128x64 of A and B
      int chunk = tid + s * 256;           // 0..1023 : row*8 + c
      int row = chunk >> 3, c = chunk & 7;
      int4v va = *(const int4v*)(Ag + (size_t)(m0 + row) * lda + kk + c * 8);
      int4v vb = *(const int4v*)(Bg + (size_t)(n0 + row) * ldb + kk + c * 8);
      *(int4v*)(sA + row * 72 + c * 8) = va;
      *(int4v*)(sB + row * 72 + c * 8) = vb;
    }
    __syncthreads();
    #pragma unroll
    for (int ks = 0; ks < 64; ks += 32) {
      short8 af[4], bf[4];
      #pragma unroll
      for (int i = 0; i < 4; i++)
        af[i] = *(const short8*)(sA + (wm * 64 + i * 16 + ln) * 72 + ks + q * 8);
      #pragma unroll
      for (int j = 0; j < 4; j++)
        bf[j] = *(const short8*)(sB + (wn * 64 + j * 16 + ln) * 72 + ks + q * 8);
      #pragma unroll
      for (int i = 0; i < 4; i++)
        #pragma unroll
        for (int j = 0; j < 4; j++)
          acc[i][j] = __builtin_amdgcn_mfma_f32_16x16x32_bf16(af[i], bf[j], acc[i][j], 0, 0, 0);
    }
  }

  #pragma unroll
  for (int j = 0; j < 4; j++) {
    const int gn = n0 + wn * 64 + j * 16 + ln;      // N index (feature e)
    const float bval = (EPI == 2) ? 0.f : bias[gn];
    #pragma unroll
    for (int i = 0; i < 4; i++) {
      const int gm = m0 + wm * 64 + i * 16 + q * 4; // M index (token row)
      #pragma unroll
      for (int r = 0; r < 4; r++) {
        const int row = gm + r;
        float vv = acc[i][j][r] + bval;
        if constexpr (EPI == 0) {
          ((unsigned short*)out0)[(size_t)row * 2048 + gn] = f2b(vv);
        } else if constexpr (EPI == 1) {
          float g = 1.f / (1.f + __expf(-vv));
          int t = row & (SEQ - 1), b = row >> 12;   // token row = b*SEQ + t
          ((unsigned short*)out0)[(size_t)(t * NB + b) * DIM + gn] = f2b(g);
          float iv = b2f(aux[(size_t)row * 2048 + gn]);
          out1[(size_t)row * 2048 + 1024 + gn] = f2b((1.f - g) * iv);
        } else if constexpr (EPI == 2) {
          int t = row & (SEQ - 1), b = row >> 12;
          ((float*)out0)[(size_t)(t * NB + b) * DIM + gn] = vv;
        } else {                                    // row = t*8 + b
          int b = row & 7, t = row >> 3;
          ((float*)out0)[(size_t)(b * SEQ + t) * DIM + gn] = vv;
        }
      }
    }
  }
}

// ---------------------------------------------------------------- scan
// 16 WGs x 256 thr = 64 waves; wave gw owns e-rows [16*gw, 16*gw+16).
// Per step: prefetch v_t/g_{t+1} (cached loads) -> poll 64 per-wave flags
// (sc0 sc1 dword) -> 32x dwordx4 sc0 sc1 m-loads with staged vmcnt waits
// -> 32 MFMAs -> tanh epi -> sb store (cached) + m-store (sc0 sc1)
// -> s_waitcnt vmcnt(0) -> flag store (sc0 sc1). No fences, no __syncthreads.
__global__ __launch_bounds__(256, 1)
void scan_kernel(const unsigned short* __restrict__ Ab,     // [1024][1024] bf16
                 const unsigned short* __restrict__ gscan,  // [t*8+b][1024] bf16
                 const float* __restrict__ vflat,           // [t*8+b][1024] f32
                 unsigned short* __restrict__ sb,           // [t*8+b][1024] bf16
                 unsigned short* __restrict__ mbuf,         // [2][8][1024] bf16
                 unsigned int* __restrict__ flags) {        // [64]
  const int tid  = threadIdx.x;
  const int lane = tid & 63;
  const int wave = tid >> 6;
  const int gw   = blockIdx.x * 4 + wave;    // 0..63
  const int e0   = gw * 16;
  const int q    = lane >> 4;
  const int ln   = lane & 15;
  const int bcl  = ln & 7;                   // clamped batch (n>=8 unused cols)
  const bool active = (ln < 8);
  const int eb = e0 + q * 4;

  short8 af[32];                             // A rows in registers (128 VGPRs)
  #pragma unroll
  for (int ks = 0; ks < 32; ks++)
    af[ks] = *(const short8*)(Ab + (size_t)(e0 + ln) * 1024 + ks * 32 + q * 8);

  const unsigned int* fpoll = flags + lane;
  unsigned int* const myflag = flags + gw;
  const float4v fz = {0.f, 0.f, 0.f, 0.f};

  for (int t = 0; t < SEQ; t++) {
    // prefetch v_t and g_{t+1} — normal (cached) loads, overlap the poll
    float4v vv = fz;
    ushort4v g4 = {0, 0, 0, 0};
    size_t rowoff = (size_t)(t * NB + bcl) * DIM + eb;
    if (active) {
      vv = *(const float4v*)(vflat + rowoff);
      if (t < SEQ - 1)
        g4 = *(const ushort4v*)(gscan + (size_t)((t + 1) * NB + bcl) * DIM + eb);
    }

    // ---- wait until all 64 waves have published m_t (flags >= t)
    {
      const unsigned int target = (unsigned int)t;
      for (;;) {
        unsigned int pv;
        asm volatile("global_load_dword %0, %1, off sc0 sc1\n\t"
                     "s_waitcnt vmcnt(0)"
                     : "=v"(pv) : "v"(fpoll) : "memory");
        if (__all((int)(pv >= target))) break;
      }
    }

    // ---- load m_t fragments straight from LLC (sc0 sc1), staged waits
    const unsigned short* mb = mbuf + (size_t)(t & 1) * (NB * DIM);
    const unsigned short* mbp = mb + bcl * DIM + q * 8;
    short8 fr[32];
    #pragma unroll
    for (int ks = 0; ks < 32; ks++)
      asm volatile("global_load_dwordx4 %0, %1, off offset:%2 sc0 sc1"
                   : "=v"(fr[ks]) : "v"(mbp), "n"(ks * 64));

    float4v a0 = fz, a1 = fz, a2 = fz, a3 = fz;
    #pragma unroll
    for (int c = 0; c < 8; c++) {
      asm volatile("s_waitcnt vmcnt(%4)"
                   : "+v"(fr[4 * c]), "+v"(fr[4 * c + 1]),
                     "+v"(fr[4 * c + 2]), "+v"(fr[4 * c + 3])
                   : "n"(28 - 4 * c));
      a0 = __builtin_amdgcn_mfma_f32_16x16x32_bf16(af[4 * c + 0], fr[4 * c + 0], a0, 0, 0, 0);
      a1 = __builtin_amdgcn_mfma_f32_16x16x32_bf16(af[4 * c + 1], fr[4 * c + 1], a1, 0, 0, 0);
      a2 = __builtin_amdgcn_mfma_f32_16x16x32_bf16(af[4 * c + 2], fr[4 * c + 2], a2, 0, 0, 0);
      a3 = __builtin_amdgcn_mfma_f32_16x16x32_bf16(af[4 * c + 3], fr[4 * c + 3], a3, 0, 0, 0);
    }

    if (active) {
      float sv[4];
      #pragma unroll
      for (int r = 0; r < 4; r++) {
        float xx = a0[r] + a1[r] + a2[r] + a3[r] + vv[r];
        float ex = __expf(-2.f * fabsf(xx));
        float th = (1.f - ex) / (1.f + ex);
        sv[r] = copysignf(th, xx);
      }
      ushort4v sp;
      #pragma unroll
      for (int r = 0; r < 4; r++) sp[r] = f2b(sv[r]);
      *(ushort4v*)(sb + rowoff) = sp;                       // state for out-proj
      if (t < SEQ - 1) {                                    // m_{t+1} = g*s
        unsigned long long mv =
            (unsigned long long)((unsigned int)f2b(b2f(g4[0]) * sv[0]) |
                                 ((unsigned int)f2b(b2f(g4[1]) * sv[1]) << 16)) |
            ((unsigned long long)((unsigned int)f2b(b2f(g4[2]) * sv[2]) |
                                  ((unsigned int)f2b(b2f(g4[3]) * sv[3]) << 16)) << 32);
        unsigned short* mn = mbuf + (size_t)((t + 1) & 1) * (NB * DIM) + bcl * DIM + eb;
        asm volatile("global_store_dwordx2 %0, %1, off sc0 sc1"
                     :: "v"(mn), "v"(mv) : "memory");
      }
    }

    if (t == SEQ - 1) break;

    // publish: drain m-stores (and sb) to the coherence point, then flag
    asm volatile("s_waitcnt vmcnt(0)" ::: "memory");
    if (lane == 0) {
      unsigned int fv = (unsigned int)(t + 1);
      asm volatile("global_store_dword %0, %1, off sc0 sc1"
                   :: "v"(myflag), "v"(fv) : "memory");
    }
  }
}

// ---------------------------------------------------------------- launch
extern "C" void kernel_launch(void* const* d_in, const int* in_sizes, int n_in,
                              void* d_out, int out_size, void* d_ws, size_t ws_size,
                              hipStream_t stream) {
  const float* x      = (const float*)d_in[0];
  const float* A      = (const float*)d_in[1];
  const float* Bm     = (const float*)d_in[2];
  const float* W_in   = (const float*)d_in[3];
  const float* b_in   = (const float*)d_in[4];
  const float* W_gate = (const float*)d_in[5];
  const float* b_gate = (const float*)d_in[6];
  const float* W_out  = (const float*)d_in[7];
  const float* b_out  = (const float*)d_in[8];

  char* ws = (char*)d_ws;
  // workspace layout (~281 MB total)
  unsigned short* xb      = (unsigned short*)(ws);                 // 64 MB (reused as sb)
  unsigned short* inpq    = (unsigned short*)(ws + 67108864);      // 128 MB [n][2048]
  unsigned short* gscan   = (unsigned short*)(ws + 201326592);     // 64 MB
  unsigned short* Wb_in   = (unsigned short*)(ws + 268435456);     // 2 MB
  unsigned short* Wb_gate = (unsigned short*)(ws + 270532608);     // 2 MB
  unsigned short* Wb_out  = (unsigned short*)(ws + 272629760);     // 2 MB
  unsigned short* Wcat    = (unsigned short*)(ws + 274726912);     // 4 MB [e][2048]
  unsigned short* Ab      = (unsigned short*)(ws + 278921216);     // 2 MB
  unsigned short* mbuf    = (unsigned short*)(ws + 281018368);     // 32 KB (2x8x1024)
  unsigned int*   flags   = (unsigned int*)(ws + 281051136);       // 256 B (64 flags)
  float*          vflat   = (float*)d_out;          // v lives in d_out pre-scan
  unsigned short* sbuf    = xb;                     // states overwrite xb

  // prep
  cast_bf16<<<(33554432 / 4 + 255) / 256, 256, 0, stream>>>(x, xb, 33554432);
  cast_bf16<<<1024, 256, 0, stream>>>(W_in,   Wb_in,   1048576);
  cast_bf16<<<1024, 256, 0, stream>>>(W_gate, Wb_gate, 1048576);
  cast_bf16<<<1024, 256, 0, stream>>>(W_out,  Wb_out,  1048576);
  build_wcat<<<1024, 256, 0, stream>>>(Bm, A, Wcat, Ab);
  zero_u32<<<(8192 + 64 + 255) / 256, 256, 0, stream>>>((unsigned int*)mbuf, 8192 + 64);

  dim3 grid(NTOK / 128, DIM / 128);
  // inp = x @ W_in^T + b_in
  gemm_nt<0><<<grid, 256, 0, stream>>>(xb, DIM, Wb_in, DIM, DIM, b_in,
                                       (void*)inpq, nullptr, nullptr);
  // g = sigmoid(inp @ W_gate^T + b_gate); q = (1-g)*inp
  gemm_nt<1><<<grid, 256, 0, stream>>>(inpq, 2048, Wb_gate, DIM, DIM, b_gate,
                                       (void*)gscan, inpq, inpq);
  // v = [inp, q] @ [B; A]^T   (K = 2048)
  gemm_nt<2><<<grid, 256, 0, stream>>>(inpq, 2048, Wcat, 2048, 2048, b_in,
                                       (void*)vflat, nullptr, nullptr);
  // sequential scan
  scan_kernel<<<16, 256, 0, stream>>>(Ab, gscan, vflat, sbuf, mbuf, flags);
  // out = states @ W_out^T + b_out  (with [t*8+b] -> [b*4096+t] permute)
  gemm_nt<3><<<grid, 256, 0, stream>>>(sbuf, DIM, Wb_out, DIM, DIM, b_out,
                                       (void*)d_out, nullptr, nullptr);
}